// Round 18
// baseline (200.474 us; speedup 1.0000x reference)
//
#include <hip/hip_runtime.h>
#include <math.h>

using bf16x8 = __attribute__((ext_vector_type(8))) short;
using f32x4  = __attribute__((ext_vector_type(4))) float;

#define MFMA(a,b,c) __builtin_amdgcn_mfma_f32_16x16x32_bf16((a),(b),(c),0,0,0)

static constexpr int NB = 4, NC = 512, NN = 4096, ND = 64;
static constexpr float LOG2E = 1.4426950408889634f;

__device__ __forceinline__ short f2bf(float f) {
  union { float f; unsigned u; } v; v.f = f;
  unsigned r = v.u + 0x7FFFu + ((v.u >> 16) & 1u);
  return (short)(r >> 16);
}

__device__ __forceinline__ unsigned cvt_pk_bf16(float a, float b) {
  unsigned r;
  asm("v_cvt_pk_bf16_f32 %0, %1, %2" : "=v"(r) : "v"(a), "v"(b));
  return r;
}

__device__ __forceinline__ void gld16(void* lds, const void* g) {
  __builtin_amdgcn_global_load_lds(
      (const __attribute__((address_space(1))) unsigned*)g,
      (__attribute__((address_space(3))) unsigned*)lds, 16, 0, 0);
}

// ---------------- kernel 1: cast weights to bf16 ----------------
__global__ void cast_w(const float* Wq, const float* Wk, const float* Wv,
                       short* Wqb, short* Wkb, short* Wvb) {
  int i = blockIdx.x * 256 + threadIdx.x;
  if (i < ND * NC) { Wqb[i] = f2bf(Wq[i]); Wkb[i] = f2bf(Wk[i]); }
  if (i < NC * NC) { Wvb[i] = f2bf(Wv[i]); }
}

// ---------------- kernel 2: x (B,C,N) f32 -> xT (B,N,C) bf16 (LDS-free) ------
__global__ __launch_bounds__(256) void transpose_x(const float* x, short* xT) {
  int b = blockIdx.z, c0 = blockIdx.y * 32, n0 = blockIdx.x * 64;
  int tid = threadIdx.x;
  int n = n0 + (tid >> 2);
  int c = c0 + (tid & 3) * 8;
  const float* xb = x + (size_t)b * NC * NN;
  bf16x8 v;
  #pragma unroll
  for (int i = 0; i < 8; i++) v[i] = f2bf(xb[(size_t)(c + i) * NN + n]);
  *(bf16x8*)(xT + ((size_t)b * NN + n) * NC + c) = v;
}

// ---------------- kernel 3: Q,K projections -> (B,N,64) bf16 ----------------
// Q pre-scaled by log2(e): downstream softmax uses exp2 (statistics-free).
__global__ __launch_bounds__(256) void proj_qk(const short* xT, const short* Wqb, const short* Wkb,
                        const float* bq, const float* bk, short* Q, short* K) {
  int b = blockIdx.y;
  int wave = threadIdx.x >> 6, lane = threadIdx.x & 63;
  int lc = lane & 15, grp = lane >> 4;
  int n0 = blockIdx.x * 64 + wave * 16;
  const short* xTb = xT + ((size_t)b * NN + n0) * NC;
  f32x4 accq[4] = {}, acck[4] = {};
  for (int c0 = 0; c0 < NC; c0 += 32) {
    bf16x8 a = *(const bf16x8*)(xTb + (size_t)lc * NC + c0 + grp * 8);
    #pragma unroll
    for (int di = 0; di < 4; di++) {
      bf16x8 wq = *(const bf16x8*)(Wqb + (size_t)(di * 16 + lc) * NC + c0 + grp * 8);
      bf16x8 wk = *(const bf16x8*)(Wkb + (size_t)(di * 16 + lc) * NC + c0 + grp * 8);
      accq[di] = MFMA(a, wq, accq[di]);
      acck[di] = MFMA(a, wk, acck[di]);
    }
  }
  short* Qb = Q + (size_t)b * NN * ND;
  short* Kb = K + (size_t)b * NN * ND;
  #pragma unroll
  for (int di = 0; di < 4; di++)
    #pragma unroll
    for (int j = 0; j < 4; j++) {
      int n = n0 + grp * 4 + j;
      int d = di * 16 + lc;
      Qb[(size_t)n * ND + d] = f2bf((accq[di][j] + bq[d]) * LOG2E);
      Kb[(size_t)n * ND + d] = f2bf(acck[di][j] + bk[d]);
    }
}

// ---------------- kernel 4: V projection -> (B,C,N) bf16 (natural layout) ----
__global__ __launch_bounds__(256, 2) void proj_v(const short* xT, const short* Wvb,
                                                 const float* bv, short* V) {
  __shared__ char lds[65536];   // dbuf: [Wv 16K | xT 16K] x2
  int b = blockIdx.z;
  int tid = threadIdx.x, wv = tid >> 6, lane = tid & 63;
  int lc = lane & 15, grp = lane >> 4;
  int e0 = blockIdx.y * 128;
  int n0 = blockIdx.x * 128;
  const char* Wg = (const char*)Wvb;
  const char* Xg = (const char*)(xT + (size_t)b * NN * NC);
  int eq = (wv >> 1) * 64, nq = (wv & 1) * 64;

  auto stage = [&](int t) {
    char* buf = lds + (t & 1) * 32768;
    int c0 = t * 64;
    #pragma unroll
    for (int i = 0; i < 4; i++) {
      int r = wv * 32 + i * 8 + (lane >> 3), g = lane & 7;
      gld16(buf + wv * 4096 + i * 1024 + lane * 16,
            Wg + (size_t)(e0 + r) * 1024 + (size_t)c0 * 2 + ((g ^ (r & 7)) * 16));
    }
    #pragma unroll
    for (int i = 0; i < 4; i++) {
      int r = wv * 32 + i * 8 + (lane >> 3), g = lane & 7;
      gld16(buf + 16384 + wv * 4096 + i * 1024 + lane * 16,
            Xg + (size_t)(n0 + r) * 1024 + (size_t)c0 * 2 + ((g ^ (r & 7)) * 16));
    }
  };

  f32x4 acc[4][4] = {};
  stage(0);
  for (int t = 0; t < 8; t++) {
    asm volatile("s_waitcnt vmcnt(0)" ::: "memory");
    __builtin_amdgcn_sched_barrier(0);
    __builtin_amdgcn_s_barrier();
    if (t < 7) stage(t + 1);
    const char* buf = lds + (t & 1) * 32768;
    bf16x8 wf[4][2], xf[4][2];
    #pragma unroll
    for (int mi = 0; mi < 4; mi++)
      #pragma unroll
      for (int ks = 0; ks < 2; ks++) {
        int r = eq + mi * 16 + lc;
        wf[mi][ks] = *(const bf16x8*)(buf + r * 128 + (((ks * 4 + grp) ^ (r & 7)) * 16));
      }
    #pragma unroll
    for (int ni = 0; ni < 4; ni++)
      #pragma unroll
      for (int ks = 0; ks < 2; ks++) {
        int r = nq + ni * 16 + lc;
        xf[ni][ks] = *(const bf16x8*)(buf + 16384 + r * 128 + (((ks * 4 + grp) ^ (r & 7)) * 16));
      }
    #pragma unroll
    for (int mi = 0; mi < 4; mi++)
      #pragma unroll
      for (int ni = 0; ni < 4; ni++) {
        acc[mi][ni] = MFMA(wf[mi][0], xf[ni][0], acc[mi][ni]);
        acc[mi][ni] = MFMA(wf[mi][1], xf[ni][1], acc[mi][ni]);
      }
  }
  short* Vbp = V + (size_t)b * NC * NN;
  #pragma unroll
  for (int mi = 0; mi < 4; mi++)
    #pragma unroll
    for (int j = 0; j < 4; j++) {
      int e = e0 + eq + mi * 16 + grp * 4 + j;
      float bb = bv[e];
      #pragma unroll
      for (int ni = 0; ni < 4; ni++) {
        int n = n0 + nq + ni * 16 + lc;
        Vbp[(size_t)e * NN + n] = f2bf(acc[mi][ni][j] + bb);
      }
    }
}

// ---------------- kernel 5: out = gamma * (softmax(QK^T) @ V^T) + x ----------
// r15 structure, e-block 128 (was 256): LDS 48K -> 3 blocks/CU = 3 waves/SIMD.
// Wave = 64m x 32e (ei=2). QK/exp per step unchanged; PV halves. Statistics-
// free softmax + VALU L partials, same swizzles, same sync skeleton.
__global__ __launch_bounds__(256, 3) void attn_out_kernel(
    const short* Q, const short* K, const short* V,
    const float* x, const float* gamma, float* out) {
  __shared__ char lds[49152];   // P dbuf 2x8K @0 | V dbuf 2x16K @16384
  int bid = blockIdx.x;
  int combo = bid & 15;                // (b, e-quarter); XCD x holds 2 V panels
  int b = combo >> 2;
  int e0 = (combo & 3) * 128;
  int m0 = (bid >> 4) * 64;
  int tid = threadIdx.x, we = tid >> 6, lane = tid & 63;
  int lc = lane & 15, grp = lane >> 4;

  char* Pl  = lds;
  char* Vb0 = lds + 16384;

  const short* Qb = Q + (size_t)b * NN * ND;
  const char* Kg = (const char*)(K + (size_t)b * NN * ND);
  const char* Vg = (const char*)(V + (size_t)b * NC * NN);

  // V staging: 16K tile (128 rows x 128B) / 256 thr / 16B = 4 chunks each
  int vR[4], vC[4];
  #pragma unroll
  for (int i = 0; i < 4; i++) {
    int ch = i * 256 + tid;
    vR[i] = ch >> 3; vC[i] = (ch & 7) ^ (vR[i] & 7);
  }
  auto stageV = [&](char* dst, int n0) {
    #pragma unroll
    for (int i = 0; i < 4; i++)
      gld16(dst + (i * 256 + tid) * 16,
            Vg + (size_t)(e0 + vR[i]) * 8192 + (size_t)n0 * 2 + vC[i] * 16);
  };

  bf16x8 qf[4][2];
  #pragma unroll
  for (int mi = 0; mi < 4; mi++)
    #pragma unroll
    for (int dk = 0; dk < 2; dk++)
      qf[mi][dk] = *(const bf16x8*)(Qb + (size_t)(m0 + mi * 16 + lc) * ND + dk * 32 + grp * 8);

  f32x4 acc[4][2] = {};    // [mi][ei]: 64m x 32e per wave
  float Lp[4] = {0.f, 0.f, 0.f, 0.f};   // VALU row-sum partials (wave's n-slice)

  // QK(t) -> exp2 -> packed bf16 -> P[t&1]; accumulate L partials from exps.
  auto qk_to_P = [&](int t, bf16x8 k0, bf16x8 k1) {
    char* Pw = Pl + (t & 1) * 8192;
    #pragma unroll
    for (int mi = 0; mi < 4; mi++) {
      f32x4 s = {0.f, 0.f, 0.f, 0.f};
      s = MFMA(k0, qf[mi][0], s);
      s = MFMA(k1, qf[mi][1], s);
      float p0 = exp2f(s[0]), p1 = exp2f(s[1]);
      float p2 = exp2f(s[2]), p3 = exp2f(s[3]);
      Lp[mi] += (p0 + p1) + (p2 + p3);
      unsigned w0 = cvt_pk_bf16(p0, p1);
      unsigned w1 = cvt_pk_bf16(p2, p3);
      int prow = mi * 16 + lc;
      int g = (2 * we + (grp >> 1)) ^ (prow & 7);
      uint2 wv; wv.x = w0; wv.y = w1;
      *(uint2*)(Pw + prow * 128 + g * 16 + (grp & 1) * 8) = wv;
    }
  };

  // ---- prologue: stage V(0); load k(0); compute P(0)
  stageV(Vb0, 0);
  {
    const char* kp = Kg + (size_t)(we * 16 + lc) * 128;
    bf16x8 k0 = *(const bf16x8*)(kp + grp * 16);
    bf16x8 k1 = *(const bf16x8*)(kp + 64 + grp * 16);
    __syncthreads();            // V(0) staged; k(0) compiler-waited
    qk_to_P(0, k0, k1);
  }
  __syncthreads();              // P(0) published

  for (int t = 0; t < 64; t++) {
    const char* Vl = Vb0 + (t & 1) * 16384;
    char* Pw = Pl + (t & 1) * 8192;

    // issue k(t+1) loads FIRST, then next-tile staging (latency spans region)
    bf16x8 kn0 = {}, kn1 = {};
    if (t < 63) {
      const char* kp = Kg + (size_t)((t + 1) * 64 + we * 16 + lc) * 128;
      kn0 = *(const bf16x8*)(kp + grp * 16);
      kn1 = *(const bf16x8*)(kp + 64 + grp * 16);
      stageV(Vb0 + ((t + 1) & 1) * 16384, (t + 1) * 64);
    }

    // ---- PV(t): read P(t), V(t) from LDS; 16 MFMA
    bf16x8 pa[4][2];
    #pragma unroll
    for (int mi = 0; mi < 4; mi++)
      #pragma unroll
      for (int ks = 0; ks < 2; ks++) {
        int row = mi * 16 + lc;
        pa[mi][ks] = *(const bf16x8*)(Pw + row * 128 + (((ks * 4 + grp) ^ (row & 7)) * 16));
      }
    __builtin_amdgcn_s_setprio(1);
    #pragma unroll
    for (int ei = 0; ei < 2; ei++) {
      int vrow = we * 32 + ei * 16 + lc;
      bf16x8 v0 = *(const bf16x8*)(Vl + vrow * 128 + ((grp ^ (vrow & 7)) * 16));
      bf16x8 v1 = *(const bf16x8*)(Vl + vrow * 128 + (((4 + grp) ^ (vrow & 7)) * 16));
      #pragma unroll
      for (int mi = 0; mi < 4; mi++) {
        acc[mi][ei] = MFMA(pa[mi][0], v0, acc[mi][ei]);
        acc[mi][ei] = MFMA(pa[mi][1], v1, acc[mi][ei]);
      }
    }
    __builtin_amdgcn_s_setprio(0);

    // ---- QK(t+1) + exp + P-write + L partials (overlaps PV by scheduler)
    if (t < 63) qk_to_P(t + 1, kn0, kn1);

    __syncthreads();   // publishes P(t+1); drains stageV(t+1); reads done
  }

  // ---- L reduction: grp-shuffle within wave, cross-wave sum via LDS.
  #pragma unroll
  for (int mi = 0; mi < 4; mi++) {
    Lp[mi] += __shfl_xor(Lp[mi], 16);
    Lp[mi] += __shfl_xor(Lp[mi], 32);
  }
  float* Lbuf = (float*)Pl;              // [4 waves][64 m] partials
  float* Lsum = (float*)(Pl + 1024);     // [64 m] 1/L totals
  if (grp == 0) {
    #pragma unroll
    for (int mi = 0; mi < 4; mi++)
      Lbuf[we * 64 + mi * 16 + lc] = Lp[mi];
  }
  __syncthreads();
  if (we == 0) {
    float s = Lbuf[lane] + Lbuf[64 + lane] + Lbuf[128 + lane] + Lbuf[192 + lane];
    Lsum[lane] = 1.0f / s;
  }
  __syncthreads();

  // ---- epilogue: out[e][m] = gamma * acc * (1/L) + x
  const float* xb = x + (size_t)b * NC * NN;
  float* ob = out + (size_t)b * NC * NN;
  float g = gamma[0];
  float Li[4][4];
  #pragma unroll
  for (int mi = 0; mi < 4; mi++) {
    f32x4 lv = *(const f32x4*)&Lsum[mi * 16 + grp * 4];
    #pragma unroll
    for (int j = 0; j < 4; j++) Li[mi][j] = lv[j];
  }
  #pragma unroll
  for (int mi = 0; mi < 4; mi++)
    #pragma unroll
    for (int ei = 0; ei < 2; ei++) {
      int e = e0 + we * 32 + ei * 16 + lc;
      int mbase = m0 + mi * 16 + grp * 4;
      f32x4 xv = *(const f32x4*)(xb + (size_t)e * NN + mbase);
      f32x4 r;
      #pragma unroll
      for (int j = 0; j < 4; j++)
        r[j] = g * (acc[mi][ei][j] * Li[mi][j]) + xv[j];
      *(f32x4*)(ob + (size_t)e * NN + mbase) = r;
    }
}

extern "C" void kernel_launch(void* const* d_in, const int* in_sizes, int n_in,
                              void* d_out, int out_size, void* d_ws, size_t ws_size,
                              hipStream_t stream) {
  const float* x     = (const float*)d_in[0];
  const float* Wq    = (const float*)d_in[1];
  const float* bq    = (const float*)d_in[2];
  const float* Wk    = (const float*)d_in[3];
  const float* bk    = (const float*)d_in[4];
  const float* Wv    = (const float*)d_in[5];
  const float* bv    = (const float*)d_in[6];
  const float* gamma = (const float*)d_in[7];
  float* out = (float*)d_out;

  char* ws = (char*)d_ws;
  size_t off = 0;
  auto alloc = [&](size_t bytes) {
    void* p = ws + off;
    off = (off + bytes + 255) & ~(size_t)255;
    return p;
  };
  short* xT   = (short*)alloc((size_t)NB * NN * NC * 2);   // 16 MB
  short* Wqb  = (short*)alloc((size_t)ND * NC * 2);
  short* Wkb  = (short*)alloc((size_t)ND * NC * 2);
  short* Wvb  = (short*)alloc((size_t)NC * NC * 2);
  short* Qb   = (short*)alloc((size_t)NB * NN * ND * 2);   // 2 MB
  short* Kb   = (short*)alloc((size_t)NB * NN * ND * 2);   // 2 MB
  short* Vb   = (short*)alloc((size_t)NB * NC * NN * 2);   // 16 MB

  cast_w<<<dim3(1024), dim3(256), 0, stream>>>(Wq, Wk, Wv, Wqb, Wkb, Wvb);
  transpose_x<<<dim3(NN / 64, NC / 32, NB), dim3(256), 0, stream>>>(x, xT);
  proj_qk<<<dim3(NN / 64, NB), dim3(256), 0, stream>>>(xT, Wqb, Wkb, bq, bk, Qb, Kb);
  proj_v<<<dim3(NN / 128, NC / 128, NB), dim3(256), 0, stream>>>(xT, Wvb, bv, Vb);
  attn_out_kernel<<<dim3(1024), dim3(256), 0, stream>>>(
      Qb, Kb, Vb, x, gamma, out);
}

// Round 19
// 153.535 us; speedup vs baseline: 1.3057x; 1.3057x over previous
//
#include <hip/hip_runtime.h>
#include <math.h>

using bf16x8 = __attribute__((ext_vector_type(8))) short;
using f32x4  = __attribute__((ext_vector_type(4))) float;

#define MFMA(a,b,c) __builtin_amdgcn_mfma_f32_16x16x32_bf16((a),(b),(c),0,0,0)

static constexpr int NB = 4, NC = 512, NN = 4096, ND = 64;
static constexpr float LOG2E = 1.4426950408889634f;

__device__ __forceinline__ short f2bf(float f) {
  union { float f; unsigned u; } v; v.f = f;
  unsigned r = v.u + 0x7FFFu + ((v.u >> 16) & 1u);
  return (short)(r >> 16);
}

__device__ __forceinline__ unsigned cvt_pk_bf16(float a, float b) {
  unsigned r;
  asm("v_cvt_pk_bf16_f32 %0, %1, %2" : "=v"(r) : "v"(a), "v"(b));
  return r;
}

__device__ __forceinline__ void gld16(void* lds, const void* g) {
  __builtin_amdgcn_global_load_lds(
      (const __attribute__((address_space(1))) unsigned*)g,
      (__attribute__((address_space(3))) unsigned*)lds, 16, 0, 0);
}

// ---------------- kernel 1: cast weights to bf16 ----------------
__global__ void cast_w(const float* Wq, const float* Wk, const float* Wv,
                       short* Wqb, short* Wkb, short* Wvb) {
  int i = blockIdx.x * 256 + threadIdx.x;
  if (i < ND * NC) { Wqb[i] = f2bf(Wq[i]); Wkb[i] = f2bf(Wk[i]); }
  if (i < NC * NC) { Wvb[i] = f2bf(Wv[i]); }
}

// ---------------- kernel 2: x (B,C,N) f32 -> xT (B,N,C) bf16 (LDS-free) ------
__global__ __launch_bounds__(256) void transpose_x(const float* x, short* xT) {
  int b = blockIdx.z, c0 = blockIdx.y * 32, n0 = blockIdx.x * 64;
  int tid = threadIdx.x;
  int n = n0 + (tid >> 2);
  int c = c0 + (tid & 3) * 8;
  const float* xb = x + (size_t)b * NC * NN;
  bf16x8 v;
  #pragma unroll
  for (int i = 0; i < 8; i++) v[i] = f2bf(xb[(size_t)(c + i) * NN + n]);
  *(bf16x8*)(xT + ((size_t)b * NN + n) * NC + c) = v;
}

// ---------------- kernel 3: Q,K projections -> (B,N,64) bf16 ----------------
// Q pre-scaled by log2(e): downstream softmax uses exp2 (statistics-free).
__global__ __launch_bounds__(256) void proj_qk(const short* xT, const short* Wqb, const short* Wkb,
                        const float* bq, const float* bk, short* Q, short* K) {
  int b = blockIdx.y;
  int wave = threadIdx.x >> 6, lane = threadIdx.x & 63;
  int lc = lane & 15, grp = lane >> 4;
  int n0 = blockIdx.x * 64 + wave * 16;
  const short* xTb = xT + ((size_t)b * NN + n0) * NC;
  f32x4 accq[4] = {}, acck[4] = {};
  for (int c0 = 0; c0 < NC; c0 += 32) {
    bf16x8 a = *(const bf16x8*)(xTb + (size_t)lc * NC + c0 + grp * 8);
    #pragma unroll
    for (int di = 0; di < 4; di++) {
      bf16x8 wq = *(const bf16x8*)(Wqb + (size_t)(di * 16 + lc) * NC + c0 + grp * 8);
      bf16x8 wk = *(const bf16x8*)(Wkb + (size_t)(di * 16 + lc) * NC + c0 + grp * 8);
      accq[di] = MFMA(a, wq, accq[di]);
      acck[di] = MFMA(a, wk, acck[di]);
    }
  }
  short* Qb = Q + (size_t)b * NN * ND;
  short* Kb = K + (size_t)b * NN * ND;
  #pragma unroll
  for (int di = 0; di < 4; di++)
    #pragma unroll
    for (int j = 0; j < 4; j++) {
      int n = n0 + grp * 4 + j;
      int d = di * 16 + lc;
      Qb[(size_t)n * ND + d] = f2bf((accq[di][j] + bq[d]) * LOG2E);
      Kb[(size_t)n * ND + d] = f2bf(acck[di][j] + bk[d]);
    }
}

// ---------------- kernel 4: V projection -> (B,C,N) bf16 (natural layout) ----
__global__ __launch_bounds__(256, 2) void proj_v(const short* xT, const short* Wvb,
                                                 const float* bv, short* V) {
  __shared__ char lds[65536];   // dbuf: [Wv 16K | xT 16K] x2
  int b = blockIdx.z;
  int tid = threadIdx.x, wv = tid >> 6, lane = tid & 63;
  int lc = lane & 15, grp = lane >> 4;
  int e0 = blockIdx.y * 128;
  int n0 = blockIdx.x * 128;
  const char* Wg = (const char*)Wvb;
  const char* Xg = (const char*)(xT + (size_t)b * NN * NC);
  int eq = (wv >> 1) * 64, nq = (wv & 1) * 64;

  auto stage = [&](int t) {
    char* buf = lds + (t & 1) * 32768;
    int c0 = t * 64;
    #pragma unroll
    for (int i = 0; i < 4; i++) {
      int r = wv * 32 + i * 8 + (lane >> 3), g = lane & 7;
      gld16(buf + wv * 4096 + i * 1024 + lane * 16,
            Wg + (size_t)(e0 + r) * 1024 + (size_t)c0 * 2 + ((g ^ (r & 7)) * 16));
    }
    #pragma unroll
    for (int i = 0; i < 4; i++) {
      int r = wv * 32 + i * 8 + (lane >> 3), g = lane & 7;
      gld16(buf + 16384 + wv * 4096 + i * 1024 + lane * 16,
            Xg + (size_t)(n0 + r) * 1024 + (size_t)c0 * 2 + ((g ^ (r & 7)) * 16));
    }
  };

  f32x4 acc[4][4] = {};
  stage(0);
  for (int t = 0; t < 8; t++) {
    asm volatile("s_waitcnt vmcnt(0)" ::: "memory");
    __builtin_amdgcn_sched_barrier(0);
    __builtin_amdgcn_s_barrier();
    if (t < 7) stage(t + 1);
    const char* buf = lds + (t & 1) * 32768;
    bf16x8 wf[4][2], xf[4][2];
    #pragma unroll
    for (int mi = 0; mi < 4; mi++)
      #pragma unroll
      for (int ks = 0; ks < 2; ks++) {
        int r = eq + mi * 16 + lc;
        wf[mi][ks] = *(const bf16x8*)(buf + r * 128 + (((ks * 4 + grp) ^ (r & 7)) * 16));
      }
    #pragma unroll
    for (int ni = 0; ni < 4; ni++)
      #pragma unroll
      for (int ks = 0; ks < 2; ks++) {
        int r = nq + ni * 16 + lc;
        xf[ni][ks] = *(const bf16x8*)(buf + 16384 + r * 128 + (((ks * 4 + grp) ^ (r & 7)) * 16));
      }
    #pragma unroll
    for (int mi = 0; mi < 4; mi++)
      #pragma unroll
      for (int ni = 0; ni < 4; ni++) {
        acc[mi][ni] = MFMA(wf[mi][0], xf[ni][0], acc[mi][ni]);
        acc[mi][ni] = MFMA(wf[mi][1], xf[ni][1], acc[mi][ni]);
      }
  }
  short* Vbp = V + (size_t)b * NC * NN;
  #pragma unroll
  for (int mi = 0; mi < 4; mi++)
    #pragma unroll
    for (int j = 0; j < 4; j++) {
      int e = e0 + eq + mi * 16 + grp * 4 + j;
      float bb = bv[e];
      #pragma unroll
      for (int ni = 0; ni < 4; ni++) {
        int n = n0 + nq + ni * 16 + lc;
        Vbp[(size_t)e * NN + n] = f2bf(acc[mi][ni][j] + bb);
      }
    }
}

// ---------------- kernel 5: out = gamma * (softmax(QK^T) @ V^T) + x ----------
// r15 verified optimum: block 64m x 256e, 4 symmetric waves (64m x 64e each),
// statistics-free softmax (P = exp2(S), no max-sub), VALU L partials from the
// exp2 outputs, merged single-barrier-pair region, P dbuf + V dbuf via gld16.
__global__ __launch_bounds__(256, 2) void attn_out_kernel(
    const short* Q, const short* K, const short* V,
    const float* x, const float* gamma, float* out) {
  __shared__ char lds[81920];   // P dbuf 2x8K @0 | V dbuf 2x32K @16384
  int bid = blockIdx.x;
  int combo = bid & 7;                 // (b, e-half) -> XCD-pinned L2 panels
  int b = combo >> 1;
  int e0 = (combo & 1) * 256;
  int m0 = (bid >> 3) * 64;
  int tid = threadIdx.x, we = tid >> 6, lane = tid & 63;
  int lc = lane & 15, grp = lane >> 4;

  char* Pl  = lds;
  char* Vb0 = lds + 16384;

  const short* Qb = Q + (size_t)b * NN * ND;
  const char* Kg = (const char*)(K + (size_t)b * NN * ND);
  const char* Vg = (const char*)(V + (size_t)b * NC * NN);

  int vR[8], vC[8];
  #pragma unroll
  for (int i = 0; i < 8; i++) {
    int ch = i * 256 + tid;
    vR[i] = ch >> 3; vC[i] = (ch & 7) ^ (vR[i] & 7);
  }
  auto stageV = [&](char* dst, int n0) {
    #pragma unroll
    for (int i = 0; i < 8; i++)
      gld16(dst + (i * 256 + tid) * 16,
            Vg + (size_t)(e0 + vR[i]) * 8192 + (size_t)n0 * 2 + vC[i] * 16);
  };

  bf16x8 qf[4][2];
  #pragma unroll
  for (int mi = 0; mi < 4; mi++)
    #pragma unroll
    for (int dk = 0; dk < 2; dk++)
      qf[mi][dk] = *(const bf16x8*)(Qb + (size_t)(m0 + mi * 16 + lc) * ND + dk * 32 + grp * 8);

  f32x4 acc[4][4] = {};    // [mi][ei]: 64m x 64e
  float Lp[4] = {0.f, 0.f, 0.f, 0.f};   // VALU row-sum partials (wave's n-slice)

  // QK(t) -> exp2 -> packed bf16 -> P[t&1]; accumulate L partials from exps.
  auto qk_to_P = [&](int t, bf16x8 k0, bf16x8 k1) {
    char* Pw = Pl + (t & 1) * 8192;
    #pragma unroll
    for (int mi = 0; mi < 4; mi++) {
      f32x4 s = {0.f, 0.f, 0.f, 0.f};
      s = MFMA(k0, qf[mi][0], s);
      s = MFMA(k1, qf[mi][1], s);
      float p0 = exp2f(s[0]), p1 = exp2f(s[1]);
      float p2 = exp2f(s[2]), p3 = exp2f(s[3]);
      Lp[mi] += (p0 + p1) + (p2 + p3);
      unsigned w0 = cvt_pk_bf16(p0, p1);
      unsigned w1 = cvt_pk_bf16(p2, p3);
      int prow = mi * 16 + lc;
      int g = (2 * we + (grp >> 1)) ^ (prow & 7);
      uint2 wv; wv.x = w0; wv.y = w1;
      *(uint2*)(Pw + prow * 128 + g * 16 + (grp & 1) * 8) = wv;
    }
  };

  // ---- prologue: stage V(0); load k(0); compute P(0)
  stageV(Vb0, 0);
  {
    const char* kp = Kg + (size_t)(we * 16 + lc) * 128;
    bf16x8 k0 = *(const bf16x8*)(kp + grp * 16);
    bf16x8 k1 = *(const bf16x8*)(kp + 64 + grp * 16);
    __syncthreads();            // V(0) staged; k(0) compiler-waited
    qk_to_P(0, k0, k1);
  }
  __syncthreads();              // P(0) published

  for (int t = 0; t < 64; t++) {
    const char* Vl = Vb0 + (t & 1) * 32768;
    char* Pw = Pl + (t & 1) * 8192;

    // issue k(t+1) loads FIRST, then next-tile staging (latency spans region)
    bf16x8 kn0 = {}, kn1 = {};
    if (t < 63) {
      const char* kp = Kg + (size_t)((t + 1) * 64 + we * 16 + lc) * 128;
      kn0 = *(const bf16x8*)(kp + grp * 16);
      kn1 = *(const bf16x8*)(kp + 64 + grp * 16);
      stageV(Vb0 + ((t + 1) & 1) * 32768, (t + 1) * 64);
    }

    // ---- PV(t): read P(t), V(t) from LDS; 32 MFMA
    bf16x8 pa[4][2];
    #pragma unroll
    for (int mi = 0; mi < 4; mi++)
      #pragma unroll
      for (int ks = 0; ks < 2; ks++) {
        int row = mi * 16 + lc;
        pa[mi][ks] = *(const bf16x8*)(Pw + row * 128 + (((ks * 4 + grp) ^ (row & 7)) * 16));
      }
    __builtin_amdgcn_s_setprio(1);
    #pragma unroll
    for (int ei = 0; ei < 4; ei++) {
      int vrow = we * 64 + ei * 16 + lc;
      bf16x8 v0 = *(const bf16x8*)(Vl + vrow * 128 + ((grp ^ (vrow & 7)) * 16));
      bf16x8 v1 = *(const bf16x8*)(Vl + vrow * 128 + (((4 + grp) ^ (vrow & 7)) * 16));
      #pragma unroll
      for (int mi = 0; mi < 4; mi++) {
        acc[mi][ei] = MFMA(pa[mi][0], v0, acc[mi][ei]);
        acc[mi][ei] = MFMA(pa[mi][1], v1, acc[mi][ei]);
      }
    }
    __builtin_amdgcn_s_setprio(0);

    // ---- QK(t+1) + exp + P-write + L partials (overlaps PV by scheduler)
    if (t < 63) qk_to_P(t + 1, kn0, kn1);

    __syncthreads();   // publishes P(t+1); drains stageV(t+1); V(t)/P(t) reads done
  }

  // ---- L reduction: grp-shuffle within wave, then cross-wave via LDS (1KB,
  // reuses the P region — safe after the loop's final barrier).
  #pragma unroll
  for (int mi = 0; mi < 4; mi++) {
    Lp[mi] += __shfl_xor(Lp[mi], 16);
    Lp[mi] += __shfl_xor(Lp[mi], 32);
  }
  float* Lbuf = (float*)Pl;          // [4 waves][64 m]
  if (grp == 0) {
    #pragma unroll
    for (int mi = 0; mi < 4; mi++)
      Lbuf[we * 64 + mi * 16 + lc] = Lp[mi];
  }
  __syncthreads();

  // ---- epilogue: out[e][m] = gamma * acc / L + x
  const float* xb = x + (size_t)b * NC * NN;
  float* ob = out + (size_t)b * NC * NN;
  float g = gamma[0];
  float Li[4][4];
  #pragma unroll
  for (int mi = 0; mi < 4; mi++) {
    f32x4 l0 = *(const f32x4*)&Lbuf[0 * 64 + mi * 16 + grp * 4];
    f32x4 l1 = *(const f32x4*)&Lbuf[1 * 64 + mi * 16 + grp * 4];
    f32x4 l2 = *(const f32x4*)&Lbuf[2 * 64 + mi * 16 + grp * 4];
    f32x4 l3 = *(const f32x4*)&Lbuf[3 * 64 + mi * 16 + grp * 4];
    #pragma unroll
    for (int j = 0; j < 4; j++)
      Li[mi][j] = 1.0f / ((l0[j] + l1[j]) + (l2[j] + l3[j]));
  }
  #pragma unroll
  for (int mi = 0; mi < 4; mi++)
    #pragma unroll
    for (int ei = 0; ei < 4; ei++) {
      int e = e0 + we * 64 + ei * 16 + lc;
      int mbase = m0 + mi * 16 + grp * 4;
      f32x4 xv = *(const f32x4*)(xb + (size_t)e * NN + mbase);
      f32x4 r;
      #pragma unroll
      for (int j = 0; j < 4; j++)
        r[j] = g * (acc[mi][ei][j] * Li[mi][j]) + xv[j];
      *(f32x4*)(ob + (size_t)e * NN + mbase) = r;
    }
}

extern "C" void kernel_launch(void* const* d_in, const int* in_sizes, int n_in,
                              void* d_out, int out_size, void* d_ws, size_t ws_size,
                              hipStream_t stream) {
  const float* x     = (const float*)d_in[0];
  const float* Wq    = (const float*)d_in[1];
  const float* bq    = (const float*)d_in[2];
  const float* Wk    = (const float*)d_in[3];
  const float* bk    = (const float*)d_in[4];
  const float* Wv    = (const float*)d_in[5];
  const float* bv    = (const float*)d_in[6];
  const float* gamma = (const float*)d_in[7];
  float* out = (float*)d_out;

  char* ws = (char*)d_ws;
  size_t off = 0;
  auto alloc = [&](size_t bytes) {
    void* p = ws + off;
    off = (off + bytes + 255) & ~(size_t)255;
    return p;
  };
  short* xT   = (short*)alloc((size_t)NB * NN * NC * 2);   // 16 MB
  short* Wqb  = (short*)alloc((size_t)ND * NC * 2);
  short* Wkb  = (short*)alloc((size_t)ND * NC * 2);
  short* Wvb  = (short*)alloc((size_t)NC * NC * 2);
  short* Qb   = (short*)alloc((size_t)NB * NN * ND * 2);   // 2 MB
  short* Kb   = (short*)alloc((size_t)NB * NN * ND * 2);   // 2 MB
  short* Vb   = (short*)alloc((size_t)NB * NC * NN * 2);   // 16 MB

  cast_w<<<dim3(1024), dim3(256), 0, stream>>>(Wq, Wk, Wv, Wqb, Wkb, Wvb);
  transpose_x<<<dim3(NN / 64, NC / 32, NB), dim3(256), 0, stream>>>(x, xT);
  proj_qk<<<dim3(NN / 64, NB), dim3(256), 0, stream>>>(xT, Wqb, Wkb, bq, bk, Qb, Kb);
  proj_v<<<dim3(NN / 128, NC / 128, NB), dim3(256), 0, stream>>>(xT, Wvb, bv, Vb);
  attn_out_kernel<<<dim3(512), dim3(256), 0, stream>>>(
      Qb, Kb, Vb, x, gamma, out);
}